// Round 7
// baseline (202.824 us; speedup 1.0000x reference)
//
#include <hip/hip_runtime.h>

#define N_NODES 16384
#define N_EDGES 131072
#define NUM_IRREPS 384      // 6*MUL
#define TE 128              // edges per block in MLP kernel (2 M-tiles per wave)

#define INV_SQRT3   0.5773502691896258f
#define INV_SQRT8   0.35355339059327373f   // 1/sqrt(N_RADIAL)
#define SC3         (0.125f * 0.35355339059327373f)  // (1/sqrt(HIDDEN)) * (1/sqrt(avg_neighbors))

typedef __attribute__((ext_vector_type(8))) __bf16 bf16x8;
typedef __attribute__((ext_vector_type(8))) unsigned short ushort8;
typedef __attribute__((ext_vector_type(4))) float f32x4;

union FragU { ushort8 u; bf16x8 b; };

__device__ __forceinline__ float silu_f(float x) {
    return x / (1.0f + __expf(-x));
}
__device__ __forceinline__ unsigned short bf16_rn(float f) {
    union { float f; unsigned int u; } c; c.f = f;
    unsigned int u = c.u + 0x7FFFu + ((c.u >> 16) & 1u);
    return (unsigned short)(u >> 16);
}
__device__ __forceinline__ float bf16_to_f(unsigned short h) {
    union { unsigned int u; float f; } c; c.u = ((unsigned int)h) << 16;
    return c.f;
}

// ---------------------------------------------------------------------------
// Pack w2 (scale 1/8) and w3 (scale SC3) into MFMA B-fragment order, hi/lo
// bf16 planes (R3/R6-verified layout). Also zeroes counts[] (replaces memset).
// ---------------------------------------------------------------------------
__global__ __launch_bounds__(256) void pack_kernel(
    const float* __restrict__ w2, const float* __restrict__ w3,
    unsigned short* __restrict__ w2p, unsigned short* __restrict__ w3p,
    int* __restrict__ counts)
{
    int t = blockIdx.x * 256 + threadIdx.x;
    if (t < N_NODES) counts[t] = 0;
    float v;
    unsigned short *hi_dst, *lo_dst;
    if (t < 4096) {
        int K = t >> 11, T = (t >> 9) & 3, lane = (t >> 3) & 63, j = t & 7;
        int k = K * 32 + (lane >> 4) * 8 + j;
        int n = T * 16 + (lane & 15);
        v = w2[k * 64 + n] * 0.125f;
        hi_dst = w2p + t; lo_dst = w2p + 4096 + t;
    } else if (t < 28672) {
        int u = t - 4096;
        int K = u / 12288; int rem = u - K * 12288;
        int T = rem >> 9, lane = (rem >> 3) & 63, j = rem & 7;
        int k = K * 32 + (lane >> 4) * 8 + j;
        int n = T * 16 + (lane & 15);
        v = w3[k * 384 + n] * SC3;
        hi_dst = w3p + u; lo_dst = w3p + 24576 + u;
    } else {
        return;
    }
    unsigned short h = bf16_rn(v);
    unsigned short l = bf16_rn(v - bf16_to_f(h));
    *hi_dst = h; *lo_dst = l;
}

// ---------------------------------------------------------------------------
// CSR construction: histogram -> scan -> fill permutation
// ---------------------------------------------------------------------------
__global__ __launch_bounds__(256) void hist_kernel(
    const int* __restrict__ receivers, int* __restrict__ counts)
{
    int e = blockIdx.x * 256 + threadIdx.x;
    if (e < N_EDGES) atomicAdd(&counts[receivers[e]], 1);
}

__global__ __launch_bounds__(256) void scan_kernel(
    const int* __restrict__ counts, int* __restrict__ offsets,
    int* __restrict__ cursor)
{
    __shared__ int wsum[4];
    const int t    = threadIdx.x;
    const int lane = t & 63;
    const int wv   = t >> 6;
    const int base = t * 64;                 // 256 * 64 = 16384
    int s = 0;
    for (int i = 0; i < 64; ++i) s += counts[base + i];
    const int own = s;
    // wave-inclusive scan
    for (int off = 1; off < 64; off <<= 1) {
        int v = __shfl_up(s, off, 64);
        if (lane >= off) s += v;
    }
    if (lane == 63) wsum[wv] = s;
    __syncthreads();
    int pre = 0;
    for (int j = 0; j < wv; ++j) pre += wsum[j];
    int run = pre + s - own;                 // exclusive prefix
    for (int i = 0; i < 64; ++i) {
        offsets[base + i] = run;
        cursor[base + i]  = run;
        run += counts[base + i];
    }
    if (t == 255) offsets[N_NODES] = run;    // == N_EDGES
}

__global__ __launch_bounds__(256) void fill_kernel(
    const int* __restrict__ receivers, int* __restrict__ cursor,
    int* __restrict__ sorted)
{
    int e = blockIdx.x * 256 + threadIdx.x;
    if (e < N_EDGES) {
        int pos = atomicAdd(&cursor[receivers[e]], 1);
        sorted[pos] = e;
    }
}

// ---------------------------------------------------------------------------
// A-fragment build: hi/lo bf16 split from fp32 LDS rows (stride 68).
// ---------------------------------------------------------------------------
__device__ __forceinline__ void build_afrags(
    const float* __restrict__ hs, int row, int quad, FragU (&ah)[2], FragU (&al)[2])
{
#pragma unroll
    for (int K = 0; K < 2; ++K) {
        const float4* p = (const float4*)&hs[row * 68 + K * 32 + quad * 8];
        float4 x0 = p[0], x1 = p[1];
        float xs[8] = {x0.x, x0.y, x0.z, x0.w, x1.x, x1.y, x1.z, x1.w};
#pragma unroll
        for (int j = 0; j < 8; ++j) {
            unsigned short h = bf16_rn(xs[j]);
            ah[K].u[j] = h;
            al[K].u[j] = bf16_rn(xs[j] - bf16_to_f(h));
        }
    }
}

// 6-MFMA bf16x3 accumulate: acc += A * B (A split hi/lo; B frags hi/lo).
__device__ __forceinline__ f32x4 mfma6(
    const FragU (&ah)[2], const FragU (&al)[2],
    const FragU& bh0, const FragU& bh1, const FragU& bl0, const FragU& bl1,
    f32x4 acc)
{
    acc = __builtin_amdgcn_mfma_f32_16x16x32_bf16(ah[0].b, bh0.b, acc, 0, 0, 0);
    acc = __builtin_amdgcn_mfma_f32_16x16x32_bf16(ah[1].b, bh1.b, acc, 0, 0, 0);
    acc = __builtin_amdgcn_mfma_f32_16x16x32_bf16(ah[0].b, bl0.b, acc, 0, 0, 0);
    acc = __builtin_amdgcn_mfma_f32_16x16x32_bf16(ah[1].b, bl1.b, acc, 0, 0, 0);
    acc = __builtin_amdgcn_mfma_f32_16x16x32_bf16(al[0].b, bh0.b, acc, 0, 0, 0);
    acc = __builtin_amdgcn_mfma_f32_16x16x32_bf16(al[1].b, bh1.b, acc, 0, 0, 0);
    return acc;
}

// ---------------------------------------------------------------------------
// Kernel 1: radial MLP over 128 sorted positions per block; wout row i =
// w(edge sorted[p_begin+i]) in bf16. Each wave owns TWO 16-edge M-tiles
// (rows wv*16 and wv*16+64) so every B-frag load feeds 12 MFMAs.
// ---------------------------------------------------------------------------
__global__ __launch_bounds__(256) void mlp_kernel(
    const float* __restrict__ radial,            // (E, 8)
    const float* __restrict__ w1,                // (8, 64)
    const unsigned short* __restrict__ w2p,      // packed hi/lo
    const unsigned short* __restrict__ w3p,      // packed hi/lo
    const int* __restrict__ sorted,              // (E,)
    unsigned short* __restrict__ wout,           // (chunk, 384) bf16, sorted order
    int p_begin)
{
    __shared__ float w1s[512];
    __shared__ float rs[TE * 9];
    __shared__ float h1s[TE * 68];   // stride 68: 16B-aligned rows
    __shared__ float h2s[TE * 68];
    __shared__ int eids[TE];

    const int t   = threadIdx.x;
    const int le0 = blockIdx.x * TE;
    const int p0  = p_begin + le0;   // global sorted-position base

    for (int i = t; i < 512; i += 256) w1s[i] = w1[i];
    if (t < TE) eids[t] = sorted[p0 + t];
    __syncthreads();
    {
        int j = t >> 1, half = t & 1;          // j in [0,128)
        float4 rv = *(const float4*)&radial[(size_t)eids[j] * 8 + half * 4];
        float* d = &rs[j * 9 + half * 4];
        d[0] = rv.x; d[1] = rv.y; d[2] = rv.z; d[3] = rv.w;
    }
    __syncthreads();

    // ---- phase 1: h1 = silu(r @ w1 / sqrt(8)), VALU, two 64-row halves ----
    for (int h = 0; h < 2; ++h) {
        const int e  = h * 64 + (t >> 2);
        const int j0 = (t & 3) * 16;
        float acc[16];
#pragma unroll
        for (int j = 0; j < 16; ++j) acc[j] = 0.0f;
#pragma unroll
        for (int k = 0; k < 8; ++k) {
            float rv = rs[e * 9 + k];
#pragma unroll
            for (int j = 0; j < 16; ++j)
                acc[j] += rv * w1s[k * 64 + j0 + j];
        }
#pragma unroll
        for (int j = 0; j < 16; ++j)
            h1s[e * 68 + j0 + j] = silu_f(acc[j] * INV_SQRT8);
    }
    __syncthreads();

    const int lane = t & 63;
    const int wv   = t >> 6;
    const int mA   = wv * 16;        // first M-tile
    const int mB   = mA + 64;        // second M-tile
    const int quad = lane >> 4;
    const int l15  = lane & 15;

    FragU ahA[2], alA[2], ahB[2], alB[2];

    build_afrags(h1s, mA + l15, quad, ahA, alA);
    build_afrags(h1s, mB + l15, quad, ahB, alB);

    // ---- phase 2: h2 = silu(h1 @ w2p) via MFMA, 4 N-tiles x 2 M-tiles ----
#pragma unroll
    for (int T = 0; T < 4; ++T) {
        FragU bh0, bh1, bl0, bl1;
        bh0.u = *(const ushort8*)(w2p +        T * 512 + lane * 8);
        bh1.u = *(const ushort8*)(w2p + 2048 + T * 512 + lane * 8);
        bl0.u = *(const ushort8*)(w2p + 4096 + T * 512 + lane * 8);
        bl1.u = *(const ushort8*)(w2p + 6144 + T * 512 + lane * 8);
        f32x4 aA = {0.f, 0.f, 0.f, 0.f};
        f32x4 aB = {0.f, 0.f, 0.f, 0.f};
        aA = mfma6(ahA, alA, bh0, bh1, bl0, bl1, aA);
        aB = mfma6(ahB, alB, bh0, bh1, bl0, bl1, aB);
#pragma unroll
        for (int r = 0; r < 4; ++r) {
            h2s[(mA + quad * 4 + r) * 68 + T * 16 + l15] = silu_f(aA[r]);
            h2s[(mB + quad * 4 + r) * 68 + T * 16 + l15] = silu_f(aB[r]);
        }
    }
    __syncthreads();

    build_afrags(h2s, mA + l15, quad, ahA, alA);
    build_afrags(h2s, mB + l15, quad, ahB, alB);

    // ---- phase 3: w = h2 @ w3p via MFMA -> wout (bf16, sorted order) ----
    for (int T = 0; T < 24; ++T) {
        FragU bh0, bh1, bl0, bl1;
        bh0.u = *(const ushort8*)(w3p +         T * 512 + lane * 8);
        bh1.u = *(const ushort8*)(w3p + 12288 + T * 512 + lane * 8);
        bl0.u = *(const ushort8*)(w3p + 24576 + T * 512 + lane * 8);
        bl1.u = *(const ushort8*)(w3p + 36864 + T * 512 + lane * 8);
        f32x4 aA = {0.f, 0.f, 0.f, 0.f};
        f32x4 aB = {0.f, 0.f, 0.f, 0.f};
        aA = mfma6(ahA, alA, bh0, bh1, bl0, bl1, aA);
        aB = mfma6(ahB, alB, bh0, bh1, bl0, bl1, aB);
#pragma unroll
        for (int r = 0; r < 4; ++r) {
            wout[(size_t)(le0 + mA + quad * 4 + r) * 384 + T * 16 + l15] = bf16_rn(aA[r]);
            wout[(size_t)(le0 + mB + quad * 4 + r) * 384 + T * 16 + l15] = bf16_rn(aB[r]);
        }
    }
}

// ---------------------------------------------------------------------------
// Kernel 2: per-node accumulation, ONE WAVE PER NODE (4 nodes/block).
// No LDS, no block sync; lane = channel; plain coalesced row stores.
// ---------------------------------------------------------------------------
__global__ __launch_bounds__(256) void accum_kernel(
    const float* __restrict__ node_feats,        // (N, 256)
    const float* __restrict__ edge_features,     // (E, 4)
    const unsigned short* __restrict__ wbuf,     // (chunk, 384) bf16, sorted order
    const int* __restrict__ senders,
    const int* __restrict__ sorted,
    const int* __restrict__ offsets,
    float* __restrict__ out,                     // (N, 768)
    int p0, int cnt)
{
    const int lane = threadIdx.x & 63;
    const int n    = blockIdx.x * 4 + (threadIdx.x >> 6);
    const int beg  = offsets[n];
    const int end  = offsets[n + 1];

    float a[12];
#pragma unroll
    for (int j = 0; j < 12; ++j) a[j] = 0.f;

    for (int i = beg; i < end; ++i) {
        if (i < p0 || i >= p0 + cnt) continue;   // outside this wbuf chunk

        const int e     = sorted[i];
        const int sidx  = senders[e];
        const float es  = edge_features[e * 4 + 0];
        const float ev0 = edge_features[e * 4 + 1];
        const float ev1 = edge_features[e * 4 + 2];
        const float ev2 = edge_features[e * 4 + 3];

        const float* nf = node_feats + (size_t)sidx * 256;
        const float s  = nf[lane];
        const float v0 = nf[64 + lane * 3 + 0];
        const float v1 = nf[64 + lane * 3 + 1];
        const float v2 = nf[64 + lane * 3 + 2];

        const unsigned short* wp = wbuf + (size_t)(i - p0) * 384;
        const float ws0 = bf16_to_f(wp[lane]);
        const float ws1 = bf16_to_f(wp[64 + lane]);
        const float ws2 = bf16_to_f(wp[128 + lane]);
        const float wv0 = bf16_to_f(wp[192 + lane]);
        const float wv1 = bf16_to_f(wp[256 + lane]);
        const float wv2 = bf16_to_f(wp[320 + lane]);

        const float dot = (v0 * ev0 + v1 * ev1 + v2 * ev2) * INV_SQRT3;

        a[0] += s * ws0;
        a[1] += s * es * ws1;
        a[2] += dot * ws2;
        a[3] += v0 * wv0; a[4] += v1 * wv0; a[5] += v2 * wv0;
        const float sw = s * wv1;
        a[6] += ev0 * sw; a[7] += ev1 * sw; a[8] += ev2 * sw;
        const float esw = es * wv2;
        a[9] += v0 * esw; a[10] += v1 * esw; a[11] += v2 * esw;
    }

    float* orow = out + (size_t)n * 768;
    const int b0 = 192 + lane * 3;
    const int b1 = 192 + (64 + lane) * 3;
    const int b2 = 192 + (128 + lane) * 3;
    if (p0 == 0) {
        orow[lane]       = a[0];
        orow[64 + lane]  = a[1];
        orow[128 + lane] = a[2];
        orow[b0 + 0] = a[3]; orow[b0 + 1] = a[4];  orow[b0 + 2] = a[5];
        orow[b1 + 0] = a[6]; orow[b1 + 1] = a[7];  orow[b1 + 2] = a[8];
        orow[b2 + 0] = a[9]; orow[b2 + 1] = a[10]; orow[b2 + 2] = a[11];
    } else {
        orow[lane]       += a[0];
        orow[64 + lane]  += a[1];
        orow[128 + lane] += a[2];
        orow[b0 + 0] += a[3]; orow[b0 + 1] += a[4];  orow[b0 + 2] += a[5];
        orow[b1 + 0] += a[6]; orow[b1 + 1] += a[7];  orow[b1 + 2] += a[8];
        orow[b2 + 0] += a[9]; orow[b2 + 1] += a[10]; orow[b2 + 2] += a[11];
    }
}

// ---------------------------------------------------------------------------
extern "C" void kernel_launch(void* const* d_in, const int* in_sizes, int n_in,
                              void* d_out, int out_size, void* d_ws, size_t ws_size,
                              hipStream_t stream) {
    const float* node_feats    = (const float*)d_in[0];
    const float* edge_features = (const float*)d_in[1];
    const float* radial        = (const float*)d_in[2];
    const float* w1            = (const float*)d_in[3];
    const float* w2            = (const float*)d_in[4];
    const float* w3            = (const float*)d_in[5];
    const int*   senders       = (const int*)d_in[6];
    const int*   receivers     = (const int*)d_in[7];
    float* out = (float*)d_out;

    // ws layout: [counts N][offsets N+1][cursor N][sorted E] | [w2p 8192][w3p 49152] | [wbuf bf16]
    int* counts  = (int*)d_ws;
    int* offsets = counts + N_NODES;
    int* cursor  = offsets + N_NODES + 1;
    int* sorted  = cursor + N_NODES;
    size_t int_bytes = (size_t)((char*)(sorted + N_EDGES) - (char*)d_ws);
    size_t pk_off = (int_bytes + 255) & ~(size_t)255;
    unsigned short* w2p = (unsigned short*)((char*)d_ws + pk_off);
    unsigned short* w3p = w2p + 8192;
    size_t wbuf_off = (pk_off + (8192 + 49152) * sizeof(unsigned short) + 255) & ~(size_t)255;
    unsigned short* wbuf = (unsigned short*)((char*)d_ws + wbuf_off);

    pack_kernel<<<112, 256, 0, stream>>>(w2, w3, w2p, w3p, counts);  // also zeroes counts
    hist_kernel<<<(N_EDGES + 255) / 256, 256, 0, stream>>>(receivers, counts);
    scan_kernel<<<1, 256, 0, stream>>>(counts, offsets, cursor);
    fill_kernel<<<(N_EDGES + 255) / 256, 256, 0, stream>>>(receivers, cursor, sorted);

    size_t avail = (ws_size > wbuf_off) ? (ws_size - wbuf_off) : 0;
    size_t max_chunk = avail / (NUM_IRREPS * sizeof(unsigned short));
    max_chunk &= ~(size_t)(TE - 1);
    int chunk = (max_chunk >= (size_t)N_EDGES) ? N_EDGES
              : (max_chunk < (size_t)TE ? TE : (int)max_chunk);

    for (int p0 = 0; p0 < N_EDGES; p0 += chunk) {
        int cnt = N_EDGES - p0;
        if (cnt > chunk) cnt = chunk;
        int nb1 = (cnt + TE - 1) / TE;
        mlp_kernel<<<nb1, 256, 0, stream>>>(radial, w1, w2p, w3p, sorted, wbuf, p0);
        accum_kernel<<<N_NODES / 4, 256, 0, stream>>>(node_feats, edge_features, wbuf,
                                                      senders, sorted, offsets, out, p0, cnt);
    }
}

// Round 8
// 202.364 us; speedup vs baseline: 1.0023x; 1.0023x over previous
//
#include <hip/hip_runtime.h>

#define N_NODES 16384
#define N_EDGES 131072
#define NUM_IRREPS 384      // 6*MUL
#define TE 128              // edges per block in MLP kernel (2 M-tiles per wave)

#define INV_SQRT3   0.5773502691896258f
#define INV_SQRT8   0.35355339059327373f   // 1/sqrt(N_RADIAL)
#define SC3         (0.125f * 0.35355339059327373f)  // (1/sqrt(HIDDEN)) * (1/sqrt(avg_neighbors))

typedef __attribute__((ext_vector_type(8))) __bf16 bf16x8;
typedef __attribute__((ext_vector_type(8))) unsigned short ushort8;
typedef __attribute__((ext_vector_type(4))) float f32x4;

union FragU { ushort8 u; bf16x8 b; };

__device__ __forceinline__ float silu_f(float x) {
    return x / (1.0f + __expf(-x));
}
__device__ __forceinline__ unsigned short bf16_rn(float f) {
    union { float f; unsigned int u; } c; c.f = f;
    unsigned int u = c.u + 0x7FFFu + ((c.u >> 16) & 1u);
    return (unsigned short)(u >> 16);
}
__device__ __forceinline__ float bf16_to_f(unsigned short h) {
    union { unsigned int u; float f; } c; c.u = ((unsigned int)h) << 16;
    return c.f;
}

// ---------------------------------------------------------------------------
// Pack w2 (scale 1/8) and w3 (scale SC3) into MFMA B-fragment order, hi/lo
// bf16 planes (R3/R6-verified layout). Also zeroes counts[] (replaces memset).
// ---------------------------------------------------------------------------
__global__ __launch_bounds__(256) void pack_kernel(
    const float* __restrict__ w2, const float* __restrict__ w3,
    unsigned short* __restrict__ w2p, unsigned short* __restrict__ w3p,
    int* __restrict__ counts)
{
    int t = blockIdx.x * 256 + threadIdx.x;
    if (t < N_NODES) counts[t] = 0;
    float v;
    unsigned short *hi_dst, *lo_dst;
    if (t < 4096) {
        int K = t >> 11, T = (t >> 9) & 3, lane = (t >> 3) & 63, j = t & 7;
        int k = K * 32 + (lane >> 4) * 8 + j;
        int n = T * 16 + (lane & 15);
        v = w2[k * 64 + n] * 0.125f;
        hi_dst = w2p + t; lo_dst = w2p + 4096 + t;
    } else if (t < 28672) {
        int u = t - 4096;
        int K = u / 12288; int rem = u - K * 12288;
        int T = rem >> 9, lane = (rem >> 3) & 63, j = rem & 7;
        int k = K * 32 + (lane >> 4) * 8 + j;
        int n = T * 16 + (lane & 15);
        v = w3[k * 384 + n] * SC3;
        hi_dst = w3p + u; lo_dst = w3p + 24576 + u;
    } else {
        return;
    }
    unsigned short h = bf16_rn(v);
    unsigned short l = bf16_rn(v - bf16_to_f(h));
    *hi_dst = h; *lo_dst = l;
}

// ---------------------------------------------------------------------------
// CSR construction: histogram -> scan -> fill permutation
// ---------------------------------------------------------------------------
__global__ __launch_bounds__(256) void hist_kernel(
    const int* __restrict__ receivers, int* __restrict__ counts)
{
    int e = blockIdx.x * 256 + threadIdx.x;
    if (e < N_EDGES) atomicAdd(&counts[receivers[e]], 1);
}

// LDS-staged scan: coalesced global IO; swizzled LDS index keeps the serial
// per-thread 64-node scan at <=2-4-way bank conflicts (was fully uncoalesced
// global loads spanning 64 cache lines per instruction).
#define SWZ(i) ((i) + ((i) >> 5))
__global__ __launch_bounds__(256) void scan_kernel(
    const int* __restrict__ counts, int* __restrict__ offsets,
    int* __restrict__ cursor)
{
    __shared__ int cnt[16896];               // 16384 + swizzle pad, 66 KB
    __shared__ int wsum[4];
    const int t    = threadIdx.x;
    const int lane = t & 63;
    const int wv   = t >> 6;

    for (int i = t; i < N_NODES; i += 256)   // coalesced load
        cnt[SWZ(i)] = counts[i];
    __syncthreads();

    const int base = t * 64;                 // 256 * 64 = 16384
    int s = 0;
    for (int i = 0; i < 64; ++i) s += cnt[SWZ(base + i)];
    const int own = s;
    // wave-inclusive scan
    for (int off = 1; off < 64; off <<= 1) {
        int v = __shfl_up(s, off, 64);
        if (lane >= off) s += v;
    }
    if (lane == 63) wsum[wv] = s;
    __syncthreads();
    int pre = 0;
    for (int j = 0; j < wv; ++j) pre += wsum[j];
    int run = pre + s - own;                 // exclusive prefix
    for (int i = 0; i < 64; ++i) {
        int idx = SWZ(base + i);
        int c = cnt[idx];                    // read before in-place overwrite
        cnt[idx] = run;
        run += c;
    }
    __syncthreads();
    for (int i = t; i < N_NODES; i += 256) { // coalesced store
        int v = cnt[SWZ(i)];
        offsets[i] = v;
        cursor[i]  = v;
    }
    if (t == 255) offsets[N_NODES] = N_EDGES;
}

__global__ __launch_bounds__(256) void fill_kernel(
    const int* __restrict__ receivers, int* __restrict__ cursor,
    int* __restrict__ sorted)
{
    int e = blockIdx.x * 256 + threadIdx.x;
    if (e < N_EDGES) {
        int pos = atomicAdd(&cursor[receivers[e]], 1);
        sorted[pos] = e;
    }
}

// ---------------------------------------------------------------------------
// A-fragment build: hi/lo bf16 split from fp32 LDS rows (stride 68).
// ---------------------------------------------------------------------------
__device__ __forceinline__ void build_afrags(
    const float* __restrict__ hs, int row, int quad, FragU (&ah)[2], FragU (&al)[2])
{
#pragma unroll
    for (int K = 0; K < 2; ++K) {
        const float4* p = (const float4*)&hs[row * 68 + K * 32 + quad * 8];
        float4 x0 = p[0], x1 = p[1];
        float xs[8] = {x0.x, x0.y, x0.z, x0.w, x1.x, x1.y, x1.z, x1.w};
#pragma unroll
        for (int j = 0; j < 8; ++j) {
            unsigned short h = bf16_rn(xs[j]);
            ah[K].u[j] = h;
            al[K].u[j] = bf16_rn(xs[j] - bf16_to_f(h));
        }
    }
}

// 6-MFMA bf16x3 accumulate: acc += A * B (A split hi/lo; B frags hi/lo).
__device__ __forceinline__ f32x4 mfma6(
    const FragU (&ah)[2], const FragU (&al)[2],
    const FragU& bh0, const FragU& bh1, const FragU& bl0, const FragU& bl1,
    f32x4 acc)
{
    acc = __builtin_amdgcn_mfma_f32_16x16x32_bf16(ah[0].b, bh0.b, acc, 0, 0, 0);
    acc = __builtin_amdgcn_mfma_f32_16x16x32_bf16(ah[1].b, bh1.b, acc, 0, 0, 0);
    acc = __builtin_amdgcn_mfma_f32_16x16x32_bf16(ah[0].b, bl0.b, acc, 0, 0, 0);
    acc = __builtin_amdgcn_mfma_f32_16x16x32_bf16(ah[1].b, bl1.b, acc, 0, 0, 0);
    acc = __builtin_amdgcn_mfma_f32_16x16x32_bf16(al[0].b, bh0.b, acc, 0, 0, 0);
    acc = __builtin_amdgcn_mfma_f32_16x16x32_bf16(al[1].b, bh1.b, acc, 0, 0, 0);
    return acc;
}

// ---------------------------------------------------------------------------
// Kernel 1: radial MLP over 128 sorted positions per block; wout row i =
// w(edge sorted[p_begin+i]) in bf16. Each wave owns TWO 16-edge M-tiles.
// h2 OVERLAYS the h1 buffer: all h-row producer/consumer traffic is
// wave-local (wave wv owns rows wv*16..+15 and 64+wv*16..+15) and A-frags
// are in registers before the overwrite. LDS 41 KB -> 3 blocks/CU.
// ---------------------------------------------------------------------------
__global__ __launch_bounds__(256) void mlp_kernel(
    const float* __restrict__ radial,            // (E, 8)
    const float* __restrict__ w1,                // (8, 64)
    const unsigned short* __restrict__ w2p,      // packed hi/lo
    const unsigned short* __restrict__ w3p,      // packed hi/lo
    const int* __restrict__ sorted,              // (E,)
    unsigned short* __restrict__ wout,           // (chunk, 384) bf16, sorted order
    int p_begin)
{
    __shared__ float w1s[512];
    __shared__ float rs[TE * 9];
    __shared__ float hs[TE * 68];    // h1, then h2 (overlaid; wave-local rows)
    __shared__ int eids[TE];

    const int t   = threadIdx.x;
    const int le0 = blockIdx.x * TE;
    const int p0  = p_begin + le0;   // global sorted-position base

    for (int i = t; i < 512; i += 256) w1s[i] = w1[i];
    if (t < TE) eids[t] = sorted[p0 + t];
    __syncthreads();
    {
        int j = t >> 1, half = t & 1;          // j in [0,128)
        float4 rv = *(const float4*)&radial[(size_t)eids[j] * 8 + half * 4];
        float* d = &rs[j * 9 + half * 4];
        d[0] = rv.x; d[1] = rv.y; d[2] = rv.z; d[3] = rv.w;
    }
    __syncthreads();

    // ---- phase 1: h1 = silu(r @ w1 / sqrt(8)), VALU, two 64-row halves ----
    for (int h = 0; h < 2; ++h) {
        const int e  = h * 64 + (t >> 2);
        const int j0 = (t & 3) * 16;
        float acc[16];
#pragma unroll
        for (int j = 0; j < 16; ++j) acc[j] = 0.0f;
#pragma unroll
        for (int k = 0; k < 8; ++k) {
            float rv = rs[e * 9 + k];
#pragma unroll
            for (int j = 0; j < 16; ++j)
                acc[j] += rv * w1s[k * 64 + j0 + j];
        }
#pragma unroll
        for (int j = 0; j < 16; ++j)
            hs[e * 68 + j0 + j] = silu_f(acc[j] * INV_SQRT8);
    }
    __syncthreads();

    const int lane = t & 63;
    const int wv   = t >> 6;
    const int mA   = wv * 16;        // first M-tile
    const int mB   = mA + 64;        // second M-tile
    const int quad = lane >> 4;
    const int l15  = lane & 15;

    FragU ahA[2], alA[2], ahB[2], alB[2];

    build_afrags(hs, mA + l15, quad, ahA, alA);
    build_afrags(hs, mB + l15, quad, ahB, alB);

    // ---- phase 2: h2 = silu(h1 @ w2p) via MFMA -> hs (overlay, wave-local) ----
#pragma unroll
    for (int T = 0; T < 4; ++T) {
        FragU bh0, bh1, bl0, bl1;
        bh0.u = *(const ushort8*)(w2p +        T * 512 + lane * 8);
        bh1.u = *(const ushort8*)(w2p + 2048 + T * 512 + lane * 8);
        bl0.u = *(const ushort8*)(w2p + 4096 + T * 512 + lane * 8);
        bl1.u = *(const ushort8*)(w2p + 6144 + T * 512 + lane * 8);
        f32x4 aA = {0.f, 0.f, 0.f, 0.f};
        f32x4 aB = {0.f, 0.f, 0.f, 0.f};
        aA = mfma6(ahA, alA, bh0, bh1, bl0, bl1, aA);
        aB = mfma6(ahB, alB, bh0, bh1, bl0, bl1, aB);
#pragma unroll
        for (int r = 0; r < 4; ++r) {
            hs[(mA + quad * 4 + r) * 68 + T * 16 + l15] = silu_f(aA[r]);
            hs[(mB + quad * 4 + r) * 68 + T * 16 + l15] = silu_f(aB[r]);
        }
    }
    __syncthreads();

    build_afrags(hs, mA + l15, quad, ahA, alA);
    build_afrags(hs, mB + l15, quad, ahB, alB);

    // ---- phase 3: w = h2 @ w3p via MFMA -> wout (bf16, sorted order) ----
    for (int T = 0; T < 24; ++T) {
        FragU bh0, bh1, bl0, bl1;
        bh0.u = *(const ushort8*)(w3p +         T * 512 + lane * 8);
        bh1.u = *(const ushort8*)(w3p + 12288 + T * 512 + lane * 8);
        bl0.u = *(const ushort8*)(w3p + 24576 + T * 512 + lane * 8);
        bl1.u = *(const ushort8*)(w3p + 36864 + T * 512 + lane * 8);
        f32x4 aA = {0.f, 0.f, 0.f, 0.f};
        f32x4 aB = {0.f, 0.f, 0.f, 0.f};
        aA = mfma6(ahA, alA, bh0, bh1, bl0, bl1, aA);
        aB = mfma6(ahB, alB, bh0, bh1, bl0, bl1, aB);
#pragma unroll
        for (int r = 0; r < 4; ++r) {
            wout[(size_t)(le0 + mA + quad * 4 + r) * 384 + T * 16 + l15] = bf16_rn(aA[r]);
            wout[(size_t)(le0 + mB + quad * 4 + r) * 384 + T * 16 + l15] = bf16_rn(aB[r]);
        }
    }
}

// ---------------------------------------------------------------------------
// Kernel 2: per-node accumulation, ONE WAVE PER NODE (4 nodes/block).
// Chunk-clipping hoisted to an interval intersection (node positions are
// contiguous in sorted order) -> branch-free inner loop.
// ---------------------------------------------------------------------------
__global__ __launch_bounds__(256) void accum_kernel(
    const float* __restrict__ node_feats,        // (N, 256)
    const float* __restrict__ edge_features,     // (E, 4)
    const unsigned short* __restrict__ wbuf,     // (chunk, 384) bf16, sorted order
    const int* __restrict__ senders,
    const int* __restrict__ sorted,
    const int* __restrict__ offsets,
    float* __restrict__ out,                     // (N, 768)
    int p0, int cnt)
{
    const int lane = threadIdx.x & 63;
    const int n    = blockIdx.x * 4 + (threadIdx.x >> 6);
    const int beg  = offsets[n];
    const int end  = offsets[n + 1];
    const int lo   = (beg > p0) ? beg : p0;
    const int hi   = (end < p0 + cnt) ? end : (p0 + cnt);

    float a[12];
#pragma unroll
    for (int j = 0; j < 12; ++j) a[j] = 0.f;

    for (int i = lo; i < hi; ++i) {
        const int e     = sorted[i];
        const int sidx  = senders[e];
        const float es  = edge_features[e * 4 + 0];
        const float ev0 = edge_features[e * 4 + 1];
        const float ev1 = edge_features[e * 4 + 2];
        const float ev2 = edge_features[e * 4 + 3];

        const float* nf = node_feats + (size_t)sidx * 256;
        const float s  = nf[lane];
        const float v0 = nf[64 + lane * 3 + 0];
        const float v1 = nf[64 + lane * 3 + 1];
        const float v2 = nf[64 + lane * 3 + 2];

        const unsigned short* wp = wbuf + (size_t)(i - p0) * 384;
        const float ws0 = bf16_to_f(wp[lane]);
        const float ws1 = bf16_to_f(wp[64 + lane]);
        const float ws2 = bf16_to_f(wp[128 + lane]);
        const float wv0 = bf16_to_f(wp[192 + lane]);
        const float wv1 = bf16_to_f(wp[256 + lane]);
        const float wv2 = bf16_to_f(wp[320 + lane]);

        const float dot = (v0 * ev0 + v1 * ev1 + v2 * ev2) * INV_SQRT3;

        a[0] += s * ws0;
        a[1] += s * es * ws1;
        a[2] += dot * ws2;
        a[3] += v0 * wv0; a[4] += v1 * wv0; a[5] += v2 * wv0;
        const float sw = s * wv1;
        a[6] += ev0 * sw; a[7] += ev1 * sw; a[8] += ev2 * sw;
        const float esw = es * wv2;
        a[9] += v0 * esw; a[10] += v1 * esw; a[11] += v2 * esw;
    }

    float* orow = out + (size_t)n * 768;
    const int b0 = 192 + lane * 3;
    const int b1 = 192 + (64 + lane) * 3;
    const int b2 = 192 + (128 + lane) * 3;
    if (p0 == 0) {
        orow[lane]       = a[0];
        orow[64 + lane]  = a[1];
        orow[128 + lane] = a[2];
        orow[b0 + 0] = a[3]; orow[b0 + 1] = a[4];  orow[b0 + 2] = a[5];
        orow[b1 + 0] = a[6]; orow[b1 + 1] = a[7];  orow[b1 + 2] = a[8];
        orow[b2 + 0] = a[9]; orow[b2 + 1] = a[10]; orow[b2 + 2] = a[11];
    } else {
        orow[lane]       += a[0];
        orow[64 + lane]  += a[1];
        orow[128 + lane] += a[2];
        orow[b0 + 0] += a[3]; orow[b0 + 1] += a[4];  orow[b0 + 2] += a[5];
        orow[b1 + 0] += a[6]; orow[b1 + 1] += a[7];  orow[b1 + 2] += a[8];
        orow[b2 + 0] += a[9]; orow[b2 + 1] += a[10]; orow[b2 + 2] += a[11];
    }
}

// ---------------------------------------------------------------------------
extern "C" void kernel_launch(void* const* d_in, const int* in_sizes, int n_in,
                              void* d_out, int out_size, void* d_ws, size_t ws_size,
                              hipStream_t stream) {
    const float* node_feats    = (const float*)d_in[0];
    const float* edge_features = (const float*)d_in[1];
    const float* radial        = (const float*)d_in[2];
    const float* w1            = (const float*)d_in[3];
    const float* w2            = (const float*)d_in[4];
    const float* w3            = (const float*)d_in[5];
    const int*   senders       = (const int*)d_in[6];
    const int*   receivers     = (const int*)d_in[7];
    float* out = (float*)d_out;

    // ws layout: [counts N][offsets N+1][cursor N][sorted E] | [w2p 8192][w3p 49152] | [wbuf bf16]
    int* counts  = (int*)d_ws;
    int* offsets = counts + N_NODES;
    int* cursor  = offsets + N_NODES + 1;
    int* sorted  = cursor + N_NODES;
    size_t int_bytes = (size_t)((char*)(sorted + N_EDGES) - (char*)d_ws);
    size_t pk_off = (int_bytes + 255) & ~(size_t)255;
    unsigned short* w2p = (unsigned short*)((char*)d_ws + pk_off);
    unsigned short* w3p = w2p + 8192;
    size_t wbuf_off = (pk_off + (8192 + 49152) * sizeof(unsigned short) + 255) & ~(size_t)255;
    unsigned short* wbuf = (unsigned short*)((char*)d_ws + wbuf_off);

    pack_kernel<<<112, 256, 0, stream>>>(w2, w3, w2p, w3p, counts);  // also zeroes counts
    hist_kernel<<<(N_EDGES + 255) / 256, 256, 0, stream>>>(receivers, counts);
    scan_kernel<<<1, 256, 0, stream>>>(counts, offsets, cursor);
    fill_kernel<<<(N_EDGES + 255) / 256, 256, 0, stream>>>(receivers, cursor, sorted);

    size_t avail = (ws_size > wbuf_off) ? (ws_size - wbuf_off) : 0;
    size_t max_chunk = avail / (NUM_IRREPS * sizeof(unsigned short));
    max_chunk &= ~(size_t)(TE - 1);
    int chunk = (max_chunk >= (size_t)N_EDGES) ? N_EDGES
              : (max_chunk < (size_t)TE ? TE : (int)max_chunk);

    for (int p0 = 0; p0 < N_EDGES; p0 += chunk) {
        int cnt = N_EDGES - p0;
        if (cnt > chunk) cnt = chunk;
        int nb1 = (cnt + TE - 1) / TE;
        mlp_kernel<<<nb1, 256, 0, stream>>>(radial, w1, w2p, w3p, sorted, wbuf, p0);
        accum_kernel<<<N_NODES / 4, 256, 0, stream>>>(node_feats, edge_features, wbuf,
                                                      senders, sorted, offsets, out, p0, cnt);
    }
}